// Round 1
// baseline (422.780 us; speedup 1.0000x reference)
//
#include <hip/hip_runtime.h>

// Layer_Hist: per-row 30-bin histogram of x[4096, 16384] fp32.
//   bin = floor(clamp(fma(x, invW, 15), 0, 29))
//   out column order: [bin0, bin29, bin1..bin28]
//
// R5: kill the LDS atomics. rocprof showed hist_kernel < 161 us (absent from
// top-5; fills at 164 us each dominate) => kernel ~166 us vs a 42.6 us HBM
// floor (256 MiB @ 6.3 TB/s) -- only 26% of achievable BW, so NOT memory
// bound. VALU (4 ops/elem ~ 3.4 us) and loads (<10 us even unhidden) are
// ruled out by arithmetic; the remaining consumer is ds_add_u32: 4096
// wave-atomics per CU against one LDS RMW pipe ~ 60-100 cyc each ~ 120-160 us.
// This also explains why R1/R3 LDS-layout changes were neutral (conflicts
// were already data-independent 2-way; the atomic RMW itself is the cost).
//
// Fix: wave-ballot CDF counting, zero LDS in the hot loop.
//   bin <= i  <=>  f < (float)(i+1)   (exact fp equivalence with the
//   clamp/floor formulation for non-NaN f => binning is bit-identical to R4)
// Per element: 1 v_fma + 29 v_cmp (VALU) + 29 s_bcnt1_b64 + 29 s_add (SALU,
// co-issues with VALU). Accumulators are wave-uniform -> SGPRs. Per-bin
// counts recovered by differencing the CDF in a tiny epilogue.
// Load pipeline (nontemporal float4, 2-stage prefetch, VPG=4) kept identical
// to R4 to isolate the atomic->ballot change.

#define NBINS   30
#define NCDF    29                      // cumulative thresholds f < 1..29
#define THREADS 256
#define ROWLEN  16384
#define VPG     4                       // float4 per group per thread
#define GROUPS  (ROWLEN / 4 / THREADS / VPG)   // 4 groups

typedef float f4 __attribute__((ext_vector_type(4)));

__global__ __launch_bounds__(THREADS) void hist_kernel(
    const float* __restrict__ x, float* __restrict__ out)
{
    __shared__ unsigned int wc[4][NCDF];   // per-wave CDF counts, 464 B

    const int t   = threadIdx.x;
    const int row = blockIdx.x;

    const float invW = 28.0f / 12.0f;   // 2.3333333f
    const float c15  = 15.0f;           // 6*invW + 1 (bin offset folded in)

    const f4* xr = (const f4*)(x + (size_t)row * ROWLEN);

    // Wave-uniform CDF accumulators: cnt[i] = #(f < i+1) over this wave's
    // 64 lanes x 64 elements. Ballot result is SGPR-uniform, so these stay
    // scalar (s_bcnt1_b64 + s_add), off the VALU critical path.
    unsigned int cnt[NCDF];
#pragma unroll
    for (int i = 0; i < NCDF; ++i) cnt[i] = 0u;

    f4 cur[VPG], nxt[VPG];
#pragma unroll
    for (int j = 0; j < VPG; ++j)
        cur[j] = __builtin_nontemporal_load(&xr[t + j * THREADS]);

#pragma unroll 1
    for (int g = 0; g < GROUPS; ++g) {
        if (g + 1 < GROUPS) {
#pragma unroll
            for (int j = 0; j < VPG; ++j)
                nxt[j] = __builtin_nontemporal_load(
                    &xr[t + ((g + 1) * VPG + j) * THREADS]);
        }
#pragma unroll
        for (int j = 0; j < VPG; ++j) {
            f4 v = cur[j];
#pragma unroll
            for (int c = 0; c < 4; ++c) {
                float f = fmaf(v[c], invW, c15);
#pragma unroll
                for (int i = 0; i < NCDF; ++i)
                    cnt[i] += (unsigned int)__popcll(
                        __ballot(f < (float)(i + 1)));
            }
        }
#pragma unroll
        for (int j = 0; j < VPG; ++j) cur[j] = nxt[j];
    }

    // Publish per-wave CDF (lane 0 holds the same uniform values as all lanes).
    if ((t & 63) == 0) {
        const int w = t >> 6;
#pragma unroll
        for (int i = 0; i < NCDF; ++i) wc[w][i] = cnt[i];
    }
    __syncthreads();

    // Difference the block-level CDF into bin counts, reorder, store.
    //   natural bin 0      = C[0]
    //   natural bin i      = C[i] - C[i-1], i = 1..28
    //   natural bin 29     = ROWLEN - C[28]
    if (t < NBINS) {
        unsigned int hi = (t < NCDF)
            ? (wc[0][t] + wc[1][t] + wc[2][t] + wc[3][t])
            : (unsigned int)ROWLEN;
        unsigned int lo = (t == 0)
            ? 0u
            : (wc[0][t - 1] + wc[1][t - 1] + wc[2][t - 1] + wc[3][t - 1]);
        const int dst = (t == 0) ? 0 : (t == NBINS - 1) ? 1 : (t + 1);
        out[(size_t)row * NBINS + dst] = (float)(hi - lo);
    }
}

extern "C" void kernel_launch(void* const* d_in, const int* in_sizes, int n_in,
                              void* d_out, int out_size, void* d_ws, size_t ws_size,
                              hipStream_t stream)
{
    const float* x  = (const float*)d_in[0];
    float* out      = (float*)d_out;
    const int rows  = in_sizes[0] / ROWLEN;   // 4096
    hist_kernel<<<rows, THREADS, 0, stream>>>(x, out);
}

// Round 2
// 328.191 us; speedup vs baseline: 1.2882x; 1.2882x over previous
//
#include <hip/hip_runtime.h>

// Layer_Hist: per-row 30-bin histogram of x[4096, 16384] fp32.
//   bin = floor(clamp(fma(x, invW, 15), 0, 29))
//   out column order: [bin0, bin29, bin1..bin28]
//
// R6: revert R5's ballot (FAILED +93 us: 29 thresholds x 2 SALU/elem
// serialize on the per-CU scalar pipe ~ 99 us). Key bound extracted from
// R5: hist kernel absent from top-5 in both rounds (fills >= 161 us) and
// K5-K4 = +93 us  =>  K4 < 68 us vs a 42.6 us HBM floor. The ds_add inner
// loop was never the bottleneck (~4096 ds_add wave-insts/CU ~ 10-25 us on
// the LDS pipe; ~7 us VALU). Residual gap to floor: occupancy -- R4's
// 31.7 KB LDS caps at 5 blocks/CU (20 waves, 62%).
//
// Fix: pack TWO threads' u16 counters per LDS word (per-thread count <= 64,
// no carry risk): thread t adds (1 << 16*(t>>7)) at h[bin*128 + (t&127)].
// Lane pairing is t <-> t+128 (always different waves), so within one
// wave-inst all 64 lanes hit 64 DISTINCT words -- bank profile identical to
// R4 (2-way, data-independent, free). LDS 31.7 -> 16.3 KB => 8 blocks/CU
// (32 waves, 100% occupancy), enforced via __launch_bounds__(256, 8)
// (live state ~32 VGPRs of float4 + temps, fits the 64-VGPR budget).
// Inner loop per element unchanged from R4: v_fma, v_med3, v_cvt_flr,
// v_lshl_add, ds_add_u32 (no-return). Cross-wave same-word ds_adds are
// atomic; fields are independent (max 64 + 64<<16, no overflow).

#define NBINS   30
#define THREADS 256
#define ROWLEN  16384
#define VPG     4                       // float4 per group per thread
#define GROUPS  (ROWLEN / 4 / THREADS / VPG)   // 4 groups
#define COLS    128                     // packed columns: 2 u16 fields/word

typedef float f4 __attribute__((ext_vector_type(4)));

__global__ __launch_bounds__(THREADS, 8) void hist_kernel(
    const float* __restrict__ x, float* __restrict__ out)
{
    __shared__ unsigned int h[NBINS * COLS];     // 15360 B
    __shared__ unsigned int partial[8 * NBINS];  //   960 B

    const int t   = threadIdx.x;
    const int row = blockIdx.x;

#pragma unroll
    for (int i = 0; i < (NBINS * COLS) / THREADS; ++i)   // 15 words/thread
        h[i * THREADS + t] = 0u;
    __syncthreads();

    const float invW = 28.0f / 12.0f;   // 2.3333333f
    const float c15  = 15.0f;           // 6*invW + 1 (bin offset folded in)
    const unsigned int inc = 1u << ((t >> 7) << 4);  // t<128: +1 ; t>=128: +1<<16
    const int col = t & (COLS - 1);

    const f4* xr = (const f4*)(x + (size_t)row * ROWLEN);

    f4 cur[VPG], nxt[VPG];
#pragma unroll
    for (int j = 0; j < VPG; ++j)
        cur[j] = __builtin_nontemporal_load(&xr[t + j * THREADS]);

#pragma unroll 1
    for (int g = 0; g < GROUPS; ++g) {
        if (g + 1 < GROUPS) {
#pragma unroll
            for (int j = 0; j < VPG; ++j)
                nxt[j] = __builtin_nontemporal_load(
                    &xr[t + ((g + 1) * VPG + j) * THREADS]);
        }
#pragma unroll
        for (int j = 0; j < VPG; ++j) {
            f4 v = cur[j];
#pragma unroll
            for (int c = 0; c < 4; ++c) {
                float f = fmaf(v[c], invW, c15);
                f = fminf(fmaxf(f, 0.0f), 29.0f);       // v_med3_f32
                int bin = __float2int_rd(f);            // v_cvt_flr_i32_f32
                atomicAdd(&h[bin * COLS + col], inc);   // ds_add_u32 (no rtn)
            }
        }
#pragma unroll
        for (int j = 0; j < VPG; ++j) cur[j] = nxt[j];
    }
    __syncthreads();

    // Stage 1: 240 threads = 30 bins x 8 groups of 16 words, rotated reads.
    // Each word holds two u16 fields (threads c and c+128).
    if (t < 240) {
        const int b = t % NBINS;
        const int g = t / NBINS;
        unsigned int s = 0;
#pragma unroll
        for (int i = 0; i < 16; ++i) {
            unsigned int w = h[b * COLS + g * 16 + ((i + b) & 15)];
            s += (w & 0xFFFFu) + (w >> 16);
        }
        partial[g * NBINS + b] = s;
    }
    __syncthreads();

    // Stage 2: 30 threads sum 8 partials, reorder, store.
    if (t < NBINS) {
        unsigned int s = 0;
#pragma unroll
        for (int g = 0; g < 8; ++g) s += partial[g * NBINS + t];
        const int dst = (t == 0) ? 0 : (t == NBINS - 1) ? 1 : (t + 1);
        out[(size_t)row * NBINS + dst] = (float)s;
    }
}

extern "C" void kernel_launch(void* const* d_in, const int* in_sizes, int n_in,
                              void* d_out, int out_size, void* d_ws, size_t ws_size,
                              hipStream_t stream)
{
    const float* x  = (const float*)d_in[0];
    float* out      = (float*)d_out;
    const int rows  = in_sizes[0] / ROWLEN;   // 4096
    hist_kernel<<<rows, THREADS, 0, stream>>>(x, out);
}